// Round 10
// baseline (150.465 us; speedup 1.0000x reference)
//
#include <hip/hip_runtime.h>

// ---------------------------------------------------------------------------
// x [2,256,64,64]  y [2,256,32,512]  z [2,128,32,512]  u [2,64,64] int
// wq1/wk1 [128,256,3,3]  wq2/wk2 [128,128,3,3]  biases [128]   out [2,4096,128]
//
// Single-plane f16 MFMA convs, fp32 accumulation. Activations halo-padded
// [B][H+2][IC/32][W+2][32] f16 (zero halos). Conv: 512-thread blocks own ALL
// 128 oc (kills 4x oc re-read); activation rows LDS-staged once per icb with
// granule XOR-swizzle (kills 3x shift re-read). Wave = 64 oc x 1 row x 32 px.
// Per rs per wave: 2 ds_read_b128 + 4 A-global (L1-hot) + 8 MFMA.
// 4 launches: prep, conv1(k+q), conv2(k+q), attn.
// ---------------------------------------------------------------------------

typedef __attribute__((ext_vector_type(8))) _Float16 f16x8;
typedef __attribute__((ext_vector_type(4))) float f32x4;
typedef __attribute__((ext_vector_type(8))) unsigned short us8;
typedef unsigned short u16;

#define MFMA16F(A, B, C) __builtin_amdgcn_mfma_f32_16x16x32_f16((A), (B), (C), 0, 0, 0)

// Weight layout: flat(icb,rs,oc,ic) = ((icb*9+rs)*128 + oc)*32 + ic.
// Activation layout: FL(b,hp,icb,wp,c) = (((b*H2+hp)*ICB+icb)*W2+wp)*32 + c.

// ---- merged prep: pack weights [0,384) + zero halos [384,511) + cvt [511,14847)
__global__ __launch_bounds__(256) void prep_k(
    const float* __restrict__ x, const float* __restrict__ y,
    const float* __restrict__ z,
    const float* __restrict__ wq1, const float* __restrict__ wq2,
    const float* __restrict__ wk1, const float* __restrict__ wk2,
    u16* __restrict__ pq1, u16* __restrict__ pq2,
    u16* __restrict__ pk1, u16* __restrict__ pk2,
    u16* __restrict__ ypad, u16* __restrict__ xpad,
    u16* __restrict__ t2k, u16* __restrict__ t1q,
    u16* __restrict__ zf16)
{
  __shared__ float tile[32][33];
  const int bid = blockIdx.x;
  const int tid = threadIdx.x;

  if (bid < 384) {
    // ---- pack all 4 weight tensors -> f16 single plane
    int t = bid * 256 + tid;
    const float* w; u16* dst; int IC, tt;
    if (t < 32768)      { w = wq1; dst = pq1; IC = 256; tt = t; }
    else if (t < 49152) { w = wq2; dst = pq2; IC = 128; tt = t - 32768; }
    else if (t < 81920) { w = wk1; dst = pk1; IC = 256; tt = t - 49152; }
    else                { w = wk2; dst = pk2; IC = 128; tt = t - 81920; }
    const int oc = tt / IC, ic = tt % IC;
    const int icb = ic >> 5, icl = ic & 31;
    #pragma unroll
    for (int rs = 0; rs < 9; ++rs) {
      float v = w[(oc * IC + ic) * 9 + rs];
      long base = (((long)icb * 9 + rs) * 128 + oc) * 32 + icl;
      dst[base] = __builtin_bit_cast(u16, (_Float16)v);
    }
  } else if (bid < 511) {
    // ---- zero halos: units of 32 u16. cum: ypad 17472, xpad 21632,
    // t2k 30368, t1q 32448.
    long u = (long)(bid - 384) * 256 + tid;
    if (u >= 32448) return;
    u16* p; int ICB, H, W2;
    if (u < 17472)      { p = ypad; ICB = 8; H = 32; W2 = 514; }
    else if (u < 21632) { u -= 17472; p = xpad; ICB = 8; H = 64; W2 = 66; }
    else if (u < 30368) { u -= 21632; p = t2k; ICB = 4; H = 32; W2 = 514; }
    else                { u -= 30368; p = t1q; ICB = 4; H = 64; W2 = 66; }
    const int H2 = H + 2;
    const long rowsN = (long)2 * ICB * 2 * W2;
    long base;
    if (u < rowsN) {
      int w = (int)(u % W2);
      int t2 = (int)(u / W2);
      int tb = t2 & 1, icb = (t2 >> 1) % ICB, b = (t2 >> 1) / ICB;
      int h = tb ? H2 - 1 : 0;
      base = ((((long)b * H2 + h) * ICB + icb) * W2 + w) * 32;
    } else {
      long v = u - rowsN;
      int side = (int)(v & 1);
      long v2 = v >> 1;
      int h = 1 + (int)(v2 % H);
      int icb = (int)((v2 / H) % ICB);
      int b = (int)(v2 / ((long)H * ICB));
      int w = side ? W2 - 1 : 0;
      base = ((((long)b * H2 + h) * ICB + icb) * W2 + w) * 32;
    }
    us8 zz = {0, 0, 0, 0, 0, 0, 0, 0};
    #pragma unroll
    for (int j = 0; j < 4; ++j)
      *reinterpret_cast<us8*>(&p[base + j * 8]) = zz;
  } else {
    // ---- transpose/cvt: y -> ypad, x -> xpad (f16 padded), z -> zf16
    const int id = bid - 511;
    const float* src; int C, H, W, wt, cb, bh, mode, H2, W2;
    u16* d16;
    if (id < 8192)       { src = y; C = 256; H = 32; W = 512; wt = id & 15;       cb = (id >> 4) & 7; bh = id >> 7; d16 = ypad; mode = 0; H2 = 34; W2 = 514; }
    else if (id < 10240) { int i2 = id - 8192;  src = x; C = 256; H = 64; W = 64; wt = i2 & 1;  cb = (i2 >> 1) & 7; bh = i2 >> 4; d16 = xpad; mode = 0; H2 = 66; W2 = 66; }
    else                 { int i3 = id - 10240; src = z; C = 128; H = 32; W = 512; wt = i3 & 15; cb = (i3 >> 4) & 3; bh = i3 >> 6; d16 = zf16; mode = 1; H2 = 0; W2 = 0; }
    const int b = bh / H, h = bh % H;
    const int w0 = wt * 32;
    const int tx = tid & 31, ty = tid >> 5;
    #pragma unroll
    for (int k2 = 0; k2 < 4; ++k2) {
      int c = cb * 32 + ty + k2 * 8;
      tile[ty + k2 * 8][tx] = src[(((long)b * C + c) * H + h) * W + w0 + tx];
    }
    __syncthreads();
    const int cp = (tid & 15) * 2;
    const int wl = tid >> 4;
    if (mode == 0) {
      const int ICB = C >> 5;
      #pragma unroll
      for (int half = 0; half < 2; ++half) {
        const int wloc = wl + half * 16;
        unsigned int lo = (unsigned int)__builtin_bit_cast(u16, (_Float16)tile[cp][wloc]);
        unsigned int hi = (unsigned int)__builtin_bit_cast(u16, (_Float16)tile[cp + 1][wloc]);
        long idx = ((((long)b * H2 + h + 1) * ICB + cb) * W2 + (w0 + wloc + 1)) * 32 + cp;
        *reinterpret_cast<unsigned int*>(&d16[idx]) = lo | (hi << 16);
      }
    } else {
      #pragma unroll
      for (int half = 0; half < 2; ++half) {
        const int wloc = wl + half * 16;
        unsigned int lo = (unsigned int)__builtin_bit_cast(u16, (_Float16)tile[cp][wloc]);
        unsigned int hi = (unsigned int)__builtin_bit_cast(u16, (_Float16)tile[cp + 1][wloc]);
        long idx = (((long)b * 32 + h) * 512 + (w0 + wloc)) * 128 + cb * 32 + cp;
        *reinterpret_cast<unsigned int*>(&d16[idx]) = lo | (hi << 16);
      }
    }
  }
}

// ---- merged conv (k blocks [0,256) + q blocks [256,320)). 512 threads.
// Block: 128 oc x RPB rows x PXS px. Wave = 64 oc x 1 row x 32 px.
// Activations LDS-staged per icb (granule swizzle g^=(p&3)); A direct global.
// OF16=1: f16 padded out [B][IH+2][4][IW+2][32] + relu.
// OF16=0: f16 flat out [B][IH][IW][128].
template<int ICB, int OF16>
__global__ __launch_bounds__(512, 4) void conv_k(
    const u16* __restrict__ inK, const u16* __restrict__ wpkK,
    const float* __restrict__ biasK, u16* __restrict__ outK,
    const u16* __restrict__ inQ, const u16* __restrict__ wpkQ,
    const float* __restrict__ biasQ, u16* __restrict__ outQ)
{
  __shared__ __align__(16) u16 smem[16384];   // 32 KB: stage / epilogue overlay

  const int tid = threadIdx.x;
  const int lane = tid & 63, wv = tid >> 6;
  const int lm = lane & 15, lq = lane >> 4;
  const int bid = blockIdx.x;

  const u16* in; const u16* wpk; const float* bias; u16* outp;
  int IH, IW, PXS, RPB, w0, h0, b, rp, pxw;
  if (bid < 256) {
    in = inK; wpk = wpkK; bias = biasK; outp = outK;
    IH = 32; IW = 512; PXS = 128; RPB = 1;
    b = bid >> 7; h0 = (bid >> 2) & 31; w0 = (bid & 3) * 128;
    rp = 0; pxw = (wv & 3) * 32;
  } else {
    const int qb = bid - 256;
    in = inQ; wpk = wpkQ; bias = biasQ; outp = outQ;
    IH = 64; IW = 64; PXS = 64; RPB = 2;
    b = qb >> 5; h0 = (qb & 31) * 2; w0 = 0;
    rp = (wv >> 1) & 1; pxw = (wv & 1) * 32;
  }
  const int ocw = wv >> 2;                 // 0..1: 64-oc half
  const int H2 = IH + 2, W2 = IW + 2, PXW2 = PXS + 2;

  f32x4 acc[4][2];   // [mf][f]
  #pragma unroll
  for (int mf = 0; mf < 4; ++mf)
    #pragma unroll
    for (int f = 0; f < 2; ++f) acc[mf][f] = (f32x4)0.f;

  for (int icb = 0; icb < ICB; ++icb) {
    __syncthreads();   // prior iter done reading smem
    // ---- stage (RPB+2) rows x (PXS+2) px x 32 ch, granule-swizzled
    const int CH = (RPB + 2) * PXW2 * 4;   // uint4 chunks
    for (int c = tid; c < CH; c += 512) {
      const int g = c & 3;
      const int p = (c >> 2) % PXW2;
      const int r = (c >> 2) / PXW2;
      uint4 v = *reinterpret_cast<const uint4*>(
          in + ((((long)b * H2 + h0 + r) * ICB + icb) * W2 + (w0 + p)) * 32 + g * 8);
      *reinterpret_cast<uint4*>(
          &smem[(r * PXW2 + p) * 32 + ((g ^ (p & 3)) * 8)]) = v;
    }
    __syncthreads();

    #pragma unroll
    for (int r = 0; r < 3; ++r)
      #pragma unroll
      for (int s = 0; s < 3; ++s) {
        const int rs = r * 3 + s;
        const int p0 = pxw + lm + s;
        const u16* brow = &smem[((rp + r) * PXW2 + p0) * 32 + ((lq ^ (p0 & 3)) * 8)];
        const f16x8 bb0 = *reinterpret_cast<const f16x8*>(brow);
        const f16x8 bb1 = *reinterpret_cast<const f16x8*>(brow + 512);  // +16 px
        const u16* wt = wpk + (((long)icb * 9 + rs) * 128 + ocw * 64 + lm) * 32 + lq * 8;
        #pragma unroll
        for (int mf = 0; mf < 4; ++mf) {
          const f16x8 a = *reinterpret_cast<const f16x8*>(wt + mf * 512);
          acc[mf][0] = MFMA16F(a, bb0, acc[mf][0]);
          acc[mf][1] = MFMA16F(a, bb1, acc[mf][1]);
        }
      }
  }

  // ---- epilogue: bias (+relu for OF16), swizzled LDS staging, f16 write
  __syncthreads();
  u16* st = smem;   // [RPB][PXS][128] u16 (32 KB), granule swz ^((px&15)<<3)
  #pragma unroll
  for (int mf = 0; mf < 4; ++mf)
    #pragma unroll
    for (int f = 0; f < 2; ++f)
      #pragma unroll
      for (int reg = 0; reg < 4; ++reg) {
        const int ocg = ocw * 64 + mf * 16 + lq * 4 + reg;
        const int px = pxw + f * 16 + lm;
        float v = acc[mf][f][reg] + bias[ocg];
        if (OF16) v = fmaxf(v, 0.f);
        st[(rp * PXS + px) * 128 + (ocg ^ ((px & 15) << 3))] =
            __builtin_bit_cast(u16, (_Float16)v);
      }
  __syncthreads();
  const int tot = RPB * PXS * 16;   // us8 chunks
  for (int c = tid; c < tot; c += 512) {
    const int o16 = c & 15;
    const int px = (c >> 4) % PXS;
    const int row = (c >> 4) / PXS;
    us8 val = *reinterpret_cast<const us8*>(
        &smem[(row * PXS + px) * 128 + ((o16 * 8) ^ ((px & 15) << 3))]);
    u16* dst;
    if (OF16)
      dst = outp + ((((long)b * H2 + h0 + row + 1) * 4 + (o16 >> 2)) * W2 + (w0 + px + 1)) * 32
          + (o16 & 3) * 8;
    else
      dst = outp + (((long)b * IH + h0 + row) * IW + w0 + px) * 128 + o16 * 8;
    *reinterpret_cast<us8*>(dst) = val;
  }
}

// ---- attention: one block per (b, n). 128 threads. All operands f16.
__global__ __launch_bounds__(128) void attn_k(
    const u16* __restrict__ qf, const u16* __restrict__ kf,
    const u16* __restrict__ zf, const int* __restrict__ u,
    float* __restrict__ out)
{
  constexpr float SCALE = 0.08838834764831845f;  // 128^-0.5
  const int n = blockIdx.x, b = blockIdx.y;
  const int t = threadIdx.x;

  __shared__ float qs[128];
  __shared__ float logit[32];
  __shared__ float el[32];

  int widx = u[b * 4096 + n];
  widx = widx < 0 ? 0 : (widx > 511 ? 511 : widx);

  qs[t] = (float)__builtin_bit_cast(_Float16, qf[((long)b * 4096 + n) * 128 + t]);
  __syncthreads();

  const int h = t >> 2, quad = t & 3;
  const u16* kcol = kf + (((long)b * 32 + h) * 512 + widx) * 128 + quad * 32;
  float p = 0.f;
  #pragma unroll
  for (int j = 0; j < 32; j += 8) {
    f16x8 kv = *reinterpret_cast<const f16x8*>(kcol + j);
    #pragma unroll
    for (int jj = 0; jj < 8; ++jj)
      p = fmaf(qs[quad * 32 + j + jj], (float)kv[jj], p);
  }
  p += __shfl_xor(p, 1);
  p += __shfl_xor(p, 2);
  if (quad == 0) logit[h] = p * SCALE;
  __syncthreads();

  float m = -3.4e38f;
  #pragma unroll
  for (int h2 = 0; h2 < 32; ++h2) m = fmaxf(m, logit[h2]);
  if (t < 32) el[t] = __expf(logit[t] - m);
  __syncthreads();
  float den = 0.f;
  #pragma unroll
  for (int h2 = 0; h2 < 32; ++h2) den += el[h2];

  const u16* zcol = zf + ((long)b * 32 * 512) * 128 + (long)widx * 128 + t;
  float o0 = 0.f, o1 = 0.f, o2 = 0.f, o3 = 0.f;
  #pragma unroll
  for (int h2 = 0; h2 < 32; h2 += 4) {
    o0 = fmaf(el[h2 + 0], (float)__builtin_bit_cast(_Float16, zcol[(long)(h2 + 0) * 512 * 128]), o0);
    o1 = fmaf(el[h2 + 1], (float)__builtin_bit_cast(_Float16, zcol[(long)(h2 + 1) * 512 * 128]), o1);
    o2 = fmaf(el[h2 + 2], (float)__builtin_bit_cast(_Float16, zcol[(long)(h2 + 2) * 512 * 128]), o2);
    o3 = fmaf(el[h2 + 3], (float)__builtin_bit_cast(_Float16, zcol[(long)(h2 + 3) * 512 * 128]), o3);
  }
  out[((long)b * 4096 + n) * 128 + t] = ((o0 + o1) + (o2 + o3)) / den;
}

extern "C" void kernel_launch(void* const* d_in, const int* in_sizes, int n_in,
                              void* d_out, int out_size, void* d_ws, size_t ws_size,
                              hipStream_t stream) {
  const float* x   = (const float*)d_in[0];
  const float* y   = (const float*)d_in[1];
  const float* z   = (const float*)d_in[2];
  const int*   u   = (const int*)  d_in[3];
  const float* wq1 = (const float*)d_in[4];
  const float* bq1 = (const float*)d_in[5];
  const float* wq2 = (const float*)d_in[6];
  const float* bq2 = (const float*)d_in[7];
  const float* wk1 = (const float*)d_in[8];
  const float* bk1 = (const float*)d_in[9];
  const float* wk2 = (const float*)d_in[10];
  const float* bk2 = (const float*)d_in[11];
  float* out = (float*)d_out;
  u16* wsu = (u16*)d_ws;

  // ---- arena (u16 offsets); total 54.2 MB
  u16* ypad  = wsu + 0;           //  8,947,712  [2][34][8][514][32] f16
  u16* xpad  = wsu + 8947712;     //  2,230,272  [2][66][8][66][32]  f16
  u16* t2k   = wsu + 11177984;    //  4,473,856  [2][34][4][514][32] f16
  u16* t1q   = wsu + 15651840;    //  1,115,136  [2][66][4][66][32]  f16
  u16* zf16  = wsu + 16766976;    //  4,194,304  [2][32][512][128]   f16
  u16* k_f16 = wsu + 20961280;    //  4,194,304  [2][32][512][128]   f16
  u16* q_f16 = wsu + 25155584;    //  1,048,576  [2,4096,128]        f16
  u16* wpk_q1 = wsu + 26204160;   //    294,912  [icb][rs][128][32]  f16
  u16* wpk_q2 = wsu + 26499072;   //    147,456
  u16* wpk_k1 = wsu + 26646528;   //    294,912
  u16* wpk_k2 = wsu + 26941440;   //    147,456  -> end 27,088,896 u16

  prep_k<<<dim3(14847), 256, 0, stream>>>(x, y, z, wq1, wq2, wk1, wk2,
                                          wpk_q1, wpk_q2, wpk_k1, wpk_k2,
                                          ypad, xpad, t2k, t1q, zf16);
  conv_k<8, 1><<<dim3(320), 512, 0, stream>>>(
      ypad, wpk_k1, bk1, t2k, xpad, wpk_q1, bq1, t1q);
  conv_k<4, 0><<<dim3(320), 512, 0, stream>>>(
      t2k, wpk_k2, bk2, k_f16, t1q, wpk_q2, bq2, q_f16);
  attn_k<<<dim3(4096, 2), 128, 0, stream>>>(q_f16, k_f16, zf16, u, out);
}

// Round 11
// 118.277 us; speedup vs baseline: 1.2721x; 1.2721x over previous
//
#include <hip/hip_runtime.h>

// ---------------------------------------------------------------------------
// x [2,256,64,64]  y [2,256,32,512]  z [2,128,32,512]  u [2,64,64] int
// wq1/wk1 [128,256,3,3]  wq2/wk2 [128,128,3,3]  biases [128]   out [2,4096,128]
//
// Single-plane f16 MFMA convs, fp32 accumulation. Activations halo-padded
// [B][H+2][IC/32][W+2][32] f16 (zero halos -> no bounds checks).
// Conv (R8 structure + occupancy x2): wave = 1 row x 32 px x 32 oc;
// block = 4 waves = 2 rows x 64 px x 32 oc; grid 1280 (5 blocks/CU).
// Weights LDS-staged pre-swizzled (18.4 KB/block); B per-rs direct from
// global (coalesced 1KB wave-loads, L2). Per rs per wave:
// 2 ds_read_b128 + 2 B-loads + 4 MFMA. 4 launches: prep, conv1, conv2, attn.
// ---------------------------------------------------------------------------

typedef __attribute__((ext_vector_type(8))) _Float16 f16x8;
typedef __attribute__((ext_vector_type(4))) float f32x4;
typedef __attribute__((ext_vector_type(8))) unsigned short us8;
typedef unsigned short u16;

#define MFMA16F(A, B, C) __builtin_amdgcn_mfma_f32_16x16x32_f16((A), (B), (C), 0, 0, 0)

// Weight layout (pre-swizzled, single plane): flat(rs,icb,ocq,j) =
//   rs*(ICB*4096) + icb*4096 + ocq*1024 + j,
// j = ((ocl*32 + ic) ^ ((ocl&7)<<3)), ocl in [0,32), ic in [0,32). (bijective)
// Activation layout: FL(b,hp,icb,wp,c) = (((b*H2+hp)*ICB+icb)*W2+wp)*32 + c.

// ---- merged prep: pack weights [0,384) + zero halos [384,511) + cvt [511,14847)
__global__ __launch_bounds__(256) void prep_k(
    const float* __restrict__ x, const float* __restrict__ y,
    const float* __restrict__ z,
    const float* __restrict__ wq1, const float* __restrict__ wq2,
    const float* __restrict__ wk1, const float* __restrict__ wk2,
    u16* __restrict__ pq1, u16* __restrict__ pq2,
    u16* __restrict__ pk1, u16* __restrict__ pk2,
    u16* __restrict__ ypad, u16* __restrict__ xpad,
    u16* __restrict__ t2k, u16* __restrict__ t1q,
    u16* __restrict__ zf16)
{
  __shared__ float tile[32][33];
  const int bid = blockIdx.x;
  const int tid = threadIdx.x;

  if (bid < 384) {
    // ---- pack all 4 weight tensors -> f16 single plane, swizzled layout
    int t = bid * 256 + tid;
    const float* w; u16* dst; int IC, tt;
    if (t < 32768)      { w = wq1; dst = pq1; IC = 256; tt = t; }
    else if (t < 49152) { w = wq2; dst = pq2; IC = 128; tt = t - 32768; }
    else if (t < 81920) { w = wk1; dst = pk1; IC = 256; tt = t - 49152; }
    else                { w = wk2; dst = pk2; IC = 128; tt = t - 81920; }
    const int oc = tt / IC, ic = tt % IC;
    const int ICB = IC >> 5;
    const int ocl = oc & 31, ocq = oc >> 5;
    const int icb = ic >> 5, icl = ic & 31;
    const int swz = ((ocl << 5) | icl) ^ ((ocl & 7) << 3);
    #pragma unroll
    for (int rs = 0; rs < 9; ++rs) {
      float v = w[(oc * IC + ic) * 9 + rs];
      long base = (long)rs * (ICB * 4096) + (long)icb * 4096
                + (long)ocq * 1024 + swz;
      dst[base] = __builtin_bit_cast(u16, (_Float16)v);
    }
  } else if (bid < 511) {
    // ---- zero halos: units of 32 u16. cum: ypad 17472, xpad 21632,
    // t2k 30368, t1q 32448.
    long u = (long)(bid - 384) * 256 + tid;
    if (u >= 32448) return;
    u16* p; int ICB, H, W2;
    if (u < 17472)      { p = ypad; ICB = 8; H = 32; W2 = 514; }
    else if (u < 21632) { u -= 17472; p = xpad; ICB = 8; H = 64; W2 = 66; }
    else if (u < 30368) { u -= 21632; p = t2k; ICB = 4; H = 32; W2 = 514; }
    else                { u -= 30368; p = t1q; ICB = 4; H = 64; W2 = 66; }
    const int H2 = H + 2;
    const long rowsN = (long)2 * ICB * 2 * W2;
    long base;
    if (u < rowsN) {
      int w = (int)(u % W2);
      int t2 = (int)(u / W2);
      int tb = t2 & 1, icb = (t2 >> 1) % ICB, b = (t2 >> 1) / ICB;
      int h = tb ? H2 - 1 : 0;
      base = ((((long)b * H2 + h) * ICB + icb) * W2 + w) * 32;
    } else {
      long v = u - rowsN;
      int side = (int)(v & 1);
      long v2 = v >> 1;
      int h = 1 + (int)(v2 % H);
      int icb = (int)((v2 / H) % ICB);
      int b = (int)(v2 / ((long)H * ICB));
      int w = side ? W2 - 1 : 0;
      base = ((((long)b * H2 + h) * ICB + icb) * W2 + w) * 32;
    }
    us8 zz = {0, 0, 0, 0, 0, 0, 0, 0};
    #pragma unroll
    for (int j = 0; j < 4; ++j)
      *reinterpret_cast<us8*>(&p[base + j * 8]) = zz;
  } else {
    // ---- transpose/cvt: y -> ypad, x -> xpad (f16 padded), z -> zf16
    const int id = bid - 511;
    const float* src; int C, H, W, wt, cb, bh, mode, H2, W2;
    u16* d16;
    if (id < 8192)       { src = y; C = 256; H = 32; W = 512; wt = id & 15;       cb = (id >> 4) & 7; bh = id >> 7; d16 = ypad; mode = 0; H2 = 34; W2 = 514; }
    else if (id < 10240) { int i2 = id - 8192;  src = x; C = 256; H = 64; W = 64; wt = i2 & 1;  cb = (i2 >> 1) & 7; bh = i2 >> 4; d16 = xpad; mode = 0; H2 = 66; W2 = 66; }
    else                 { int i3 = id - 10240; src = z; C = 128; H = 32; W = 512; wt = i3 & 15; cb = (i3 >> 4) & 3; bh = i3 >> 6; d16 = zf16; mode = 1; H2 = 0; W2 = 0; }
    const int b = bh / H, h = bh % H;
    const int w0 = wt * 32;
    const int tx = tid & 31, ty = tid >> 5;
    #pragma unroll
    for (int k2 = 0; k2 < 4; ++k2) {
      int c = cb * 32 + ty + k2 * 8;
      tile[ty + k2 * 8][tx] = src[(((long)b * C + c) * H + h) * W + w0 + tx];
    }
    __syncthreads();
    const int cp = (tid & 15) * 2;
    const int wl = tid >> 4;
    if (mode == 0) {
      const int ICB = C >> 5;
      #pragma unroll
      for (int half = 0; half < 2; ++half) {
        const int wloc = wl + half * 16;
        unsigned int lo = (unsigned int)__builtin_bit_cast(u16, (_Float16)tile[cp][wloc]);
        unsigned int hi = (unsigned int)__builtin_bit_cast(u16, (_Float16)tile[cp + 1][wloc]);
        long idx = ((((long)b * H2 + h + 1) * ICB + cb) * W2 + (w0 + wloc + 1)) * 32 + cp;
        *reinterpret_cast<unsigned int*>(&d16[idx]) = lo | (hi << 16);
      }
    } else {
      #pragma unroll
      for (int half = 0; half < 2; ++half) {
        const int wloc = wl + half * 16;
        unsigned int lo = (unsigned int)__builtin_bit_cast(u16, (_Float16)tile[cp][wloc]);
        unsigned int hi = (unsigned int)__builtin_bit_cast(u16, (_Float16)tile[cp + 1][wloc]);
        long idx = (((long)b * 32 + h) * 512 + (w0 + wloc)) * 128 + cb * 32 + cp;
        *reinterpret_cast<unsigned int*>(&d16[idx]) = lo | (hi << 16);
      }
    }
  }
}

// ---- merged conv (k blocks [0,1024) + q blocks [1024,1280)).
// Block: 32 oc (ocq) x 2 rows x 64 px; wave = 1 row x 32 px x 32 oc.
// OF16=1: f16 padded out [B][IH+2][4][IW+2][32] + relu.
// OF16=0: f16 flat out [B][IH][IW][128].
template<int ICB, int OF16>
__global__ __launch_bounds__(256, 4) void conv_k(
    const u16* __restrict__ inK, const u16* __restrict__ wpkK,
    const float* __restrict__ biasK, u16* __restrict__ outK,
    const u16* __restrict__ inQ, const u16* __restrict__ wpkQ,
    const float* __restrict__ biasQ, u16* __restrict__ outQ)
{
  __shared__ __align__(16) u16 smem[9216];   // 18432 B: 9 rs x 1024 (32oc x 32ic)

  const int tid = threadIdx.x;
  const int lane = tid & 63, wv = tid >> 6;
  const int lm = lane & 15, lq = lane >> 4;
  const int bid = blockIdx.x;

  const u16* in; const u16* wpk; const float* bias; u16* outp;
  int IH, IW, w0, hb, b, ocq;
  constexpr int PXS = 64, RPB = 2;
  if (bid < 1024) {
    in = inK; wpk = wpkK; bias = biasK; outp = outK;
    IH = 32; IW = 512;
    b = bid >> 9; hb = ((bid >> 5) & 15) * 2;
    w0 = ((bid >> 2) & 7) * 64; ocq = bid & 3;
  } else {
    const int qb = bid - 1024;
    in = inQ; wpk = wpkQ; bias = biasQ; outp = outQ;
    IH = 64; IW = 64;
    b = qb >> 7; hb = ((qb >> 2) & 31) * 2;
    w0 = 0; ocq = qb & 3;
  }
  const int H2 = IH + 2, W2 = IW + 2;
  const int rp = wv >> 1;               // wave's row within block (0..1)
  const int pxw = (wv & 1) * 32;        // wave's 32-px group

  // A-frag swizzled offsets (mf=0/1); (16+lm)&7 == lm&7 so mf=1 is +512.
  const int aswz0 = (lm * 32 + lq * 8) ^ ((lm & 7) << 3);
  const int aswz1 = aswz0 + 512;

  f32x4 acc[2][2];   // [mf][f]
  #pragma unroll
  for (int mf = 0; mf < 2; ++mf)
    #pragma unroll
    for (int f = 0; f < 2; ++f) acc[mf][f] = (f32x4)0.f;

  for (int icb = 0; icb < ICB; ++icb) {
    __syncthreads();
    // ---- stage this icb's 9 pre-swizzled 32x32 weight tiles (linear copy)
    #pragma unroll
    for (int c0 = 0; c0 < 5; ++c0) {
      const int c = c0 * 256 + tid;
      if (c < 1152) {
        const int rs2 = c >> 7;
        const int j = (c & 127) * 8;
        *reinterpret_cast<uint4*>(&smem[rs2 * 1024 + j]) =
            *reinterpret_cast<const uint4*>(
                wpk + (long)rs2 * (ICB * 4096) + (long)icb * 4096 + ocq * 1024 + j);
      }
    }
    // ---- per-lane row base pointers (padded rows hb+rp .. hb+rp+2)
    const u16* rb[3];
    #pragma unroll
    for (int r = 0; r < 3; ++r)
      rb[r] = in + ((((long)b * H2 + hb + rp + r) * ICB + icb) * W2 + (w0 + pxw + lm)) * 32
            + lq * 8;
    __syncthreads();

    #pragma unroll
    for (int r = 0; r < 3; ++r)
      #pragma unroll
      for (int s = 0; s < 3; ++s) {
        const int rs = r * 3 + s;
        const f16x8 bb0 = *reinterpret_cast<const f16x8*>(rb[r] + s * 32);
        const f16x8 bb1 = *reinterpret_cast<const f16x8*>(rb[r] + (16 + s) * 32);
        const int tb = rs * 1024;
        const f16x8 a0 = *reinterpret_cast<const f16x8*>(&smem[tb + aswz0]);
        const f16x8 a1 = *reinterpret_cast<const f16x8*>(&smem[tb + aswz1]);
        acc[0][0] = MFMA16F(a0, bb0, acc[0][0]);
        acc[0][1] = MFMA16F(a0, bb1, acc[0][1]);
        acc[1][0] = MFMA16F(a1, bb0, acc[1][0]);
        acc[1][1] = MFMA16F(a1, bb1, acc[1][1]);
      }
  }

  // ---- epilogue: bias (+relu for OF16), swizzled LDS staging, f16 write
  __syncthreads();
  u16* st = smem;   // [RPB][PXS][32] u16 (8 KB)
  #pragma unroll
  for (int mf = 0; mf < 2; ++mf)
    #pragma unroll
    for (int f = 0; f < 2; ++f)
      #pragma unroll
      for (int reg = 0; reg < 4; ++reg) {
        const int ocl = mf * 16 + lq * 4 + reg;
        const int px = pxw + f * 16 + lm;
        float v = acc[mf][f][reg] + bias[ocq * 32 + ocl];
        if (OF16) v = fmaxf(v, 0.f);
        st[(rp * PXS + px) * 32 + (ocl ^ ((px & 3) << 3))] =
            __builtin_bit_cast(u16, (_Float16)v);
      }
  __syncthreads();
  const int tot = RPB * PXS * 4;   // us8 chunks
  for (int i = tid; i < tot; i += 256) {
    const int o8 = i & 3, pxr = i >> 2;
    const int px = pxr % PXS, row = pxr / PXS;
    us8 val = *reinterpret_cast<const us8*>(
        &st[(row * PXS + px) * 32 + ((o8 * 8) ^ ((px & 3) << 3))]);
    u16* dst;
    if (OF16)
      dst = outp + ((((long)b * H2 + hb + row + 1) * 4 + ocq) * W2 + (w0 + px + 1)) * 32
          + o8 * 8;
    else
      dst = outp + (((long)b * IH + hb + row) * IW + w0 + px) * 128 + ocq * 32 + o8 * 8;
    *reinterpret_cast<us8*>(dst) = val;
  }
}

// ---- attention: one block per (b, n). 128 threads. All operands f16.
__global__ __launch_bounds__(128) void attn_k(
    const u16* __restrict__ qf, const u16* __restrict__ kf,
    const u16* __restrict__ zf, const int* __restrict__ u,
    float* __restrict__ out)
{
  constexpr float SCALE = 0.08838834764831845f;  // 128^-0.5
  const int n = blockIdx.x, b = blockIdx.y;
  const int t = threadIdx.x;

  __shared__ float qs[128];
  __shared__ float logit[32];
  __shared__ float el[32];

  int widx = u[b * 4096 + n];
  widx = widx < 0 ? 0 : (widx > 511 ? 511 : widx);

  qs[t] = (float)__builtin_bit_cast(_Float16, qf[((long)b * 4096 + n) * 128 + t]);
  __syncthreads();

  const int h = t >> 2, quad = t & 3;
  const u16* kcol = kf + (((long)b * 32 + h) * 512 + widx) * 128 + quad * 32;
  float p = 0.f;
  #pragma unroll
  for (int j = 0; j < 32; j += 8) {
    f16x8 kv = *reinterpret_cast<const f16x8*>(kcol + j);
    #pragma unroll
    for (int jj = 0; jj < 8; ++jj)
      p = fmaf(qs[quad * 32 + j + jj], (float)kv[jj], p);
  }
  p += __shfl_xor(p, 1);
  p += __shfl_xor(p, 2);
  if (quad == 0) logit[h] = p * SCALE;
  __syncthreads();

  float m = -3.4e38f;
  #pragma unroll
  for (int h2 = 0; h2 < 32; ++h2) m = fmaxf(m, logit[h2]);
  if (t < 32) el[t] = __expf(logit[t] - m);
  __syncthreads();
  float den = 0.f;
  #pragma unroll
  for (int h2 = 0; h2 < 32; ++h2) den += el[h2];

  const u16* zcol = zf + ((long)b * 32 * 512) * 128 + (long)widx * 128 + t;
  float o0 = 0.f, o1 = 0.f, o2 = 0.f, o3 = 0.f;
  #pragma unroll
  for (int h2 = 0; h2 < 32; h2 += 4) {
    o0 = fmaf(el[h2 + 0], (float)__builtin_bit_cast(_Float16, zcol[(long)(h2 + 0) * 512 * 128]), o0);
    o1 = fmaf(el[h2 + 1], (float)__builtin_bit_cast(_Float16, zcol[(long)(h2 + 1) * 512 * 128]), o1);
    o2 = fmaf(el[h2 + 2], (float)__builtin_bit_cast(_Float16, zcol[(long)(h2 + 2) * 512 * 128]), o2);
    o3 = fmaf(el[h2 + 3], (float)__builtin_bit_cast(_Float16, zcol[(long)(h2 + 3) * 512 * 128]), o3);
  }
  out[((long)b * 4096 + n) * 128 + t] = ((o0 + o1) + (o2 + o3)) / den;
}

extern "C" void kernel_launch(void* const* d_in, const int* in_sizes, int n_in,
                              void* d_out, int out_size, void* d_ws, size_t ws_size,
                              hipStream_t stream) {
  const float* x   = (const float*)d_in[0];
  const float* y   = (const float*)d_in[1];
  const float* z   = (const float*)d_in[2];
  const int*   u   = (const int*)  d_in[3];
  const float* wq1 = (const float*)d_in[4];
  const float* bq1 = (const float*)d_in[5];
  const float* wq2 = (const float*)d_in[6];
  const float* bq2 = (const float*)d_in[7];
  const float* wk1 = (const float*)d_in[8];
  const float* bk1 = (const float*)d_in[9];
  const float* wk2 = (const float*)d_in[10];
  const float* bk2 = (const float*)d_in[11];
  float* out = (float*)d_out;
  u16* wsu = (u16*)d_ws;

  // ---- arena (u16 offsets); total 54.2 MB
  u16* ypad  = wsu + 0;           //  8,947,712  [2][34][8][514][32] f16
  u16* xpad  = wsu + 8947712;     //  2,230,272  [2][66][8][66][32]  f16
  u16* t2k   = wsu + 11177984;    //  4,473,856  [2][34][4][514][32] f16
  u16* t1q   = wsu + 15651840;    //  1,115,136  [2][66][4][66][32]  f16
  u16* zf16  = wsu + 16766976;    //  4,194,304  [2][32][512][128]   f16
  u16* k_f16 = wsu + 20961280;    //  4,194,304  [2][32][512][128]   f16
  u16* q_f16 = wsu + 25155584;    //  1,048,576  [2,4096,128]        f16
  u16* wpk_q1 = wsu + 26204160;   //    294,912  (pre-swizzled)
  u16* wpk_q2 = wsu + 26499072;   //    147,456
  u16* wpk_k1 = wsu + 26646528;   //    294,912
  u16* wpk_k2 = wsu + 26941440;   //    147,456  -> end 27,088,896 u16

  prep_k<<<dim3(14847), 256, 0, stream>>>(x, y, z, wq1, wq2, wk1, wk2,
                                          wpk_q1, wpk_q2, wpk_k1, wpk_k2,
                                          ypad, xpad, t2k, t1q, zf16);
  conv_k<8, 1><<<dim3(1280), 256, 0, stream>>>(
      ypad, wpk_k1, bk1, t2k, xpad, wpk_q1, bq1, t1q);
  conv_k<4, 0><<<dim3(1280), 256, 0, stream>>>(
      t2k, wpk_k2, bk2, k_f16, t1q, wpk_q2, bq2, q_f16);
  attn_k<<<dim3(4096, 2), 128, 0, stream>>>(q_f16, k_f16, zf16, u, out);
}

// Round 12
// 117.970 us; speedup vs baseline: 1.2755x; 1.0026x over previous
//
#include <hip/hip_runtime.h>

// ---------------------------------------------------------------------------
// x [2,256,64,64]  y [2,256,32,512]  z [2,128,32,512]  u [2,64,64] int
// wq1/wk1 [128,256,3,3]  wq2/wk2 [128,128,3,3]  biases [128]   out [2,4096,128]
//
// Single-plane f16 MFMA convs, fp32 accumulation. Activations halo-padded
// [B][H+2][IC/32][W+2][32] f16 (zero halos -> no bounds checks).
// Conv: wave = 1 row x 32 px x 32 oc; block = 4 waves; grid 1280.
// XCD-aware bijective block swizzle (wid = (bid%8)*160 + bid/8): each XCD
// gets a contiguous work slice whose input working set (~3 MB) fits its
// private 4 MB L2 -> ocq/halo/shift re-reads become L2 hits, not HBM.
// Weights LDS-staged pre-swizzled (18.4 KB/block); B per-rs direct from
// global. 4 launches: prep, conv1, conv2, attn.
// ---------------------------------------------------------------------------

typedef __attribute__((ext_vector_type(8))) _Float16 f16x8;
typedef __attribute__((ext_vector_type(4))) float f32x4;
typedef __attribute__((ext_vector_type(8))) unsigned short us8;
typedef unsigned short u16;

#define MFMA16F(A, B, C) __builtin_amdgcn_mfma_f32_16x16x32_f16((A), (B), (C), 0, 0, 0)

// Weight layout (pre-swizzled, single plane): flat(rs,icb,ocq,j) =
//   rs*(ICB*4096) + icb*4096 + ocq*1024 + j,
// j = ((ocl*32 + ic) ^ ((ocl&7)<<3)), ocl in [0,32), ic in [0,32). (bijective)
// Activation layout: FL(b,hp,icb,wp,c) = (((b*H2+hp)*ICB+icb)*W2+wp)*32 + c.

// ---- merged prep: pack weights [0,384) + zero halos [384,511) + cvt [511,14847)
__global__ __launch_bounds__(256) void prep_k(
    const float* __restrict__ x, const float* __restrict__ y,
    const float* __restrict__ z,
    const float* __restrict__ wq1, const float* __restrict__ wq2,
    const float* __restrict__ wk1, const float* __restrict__ wk2,
    u16* __restrict__ pq1, u16* __restrict__ pq2,
    u16* __restrict__ pk1, u16* __restrict__ pk2,
    u16* __restrict__ ypad, u16* __restrict__ xpad,
    u16* __restrict__ t2k, u16* __restrict__ t1q,
    u16* __restrict__ zf16)
{
  __shared__ float tile[32][33];
  const int bid = blockIdx.x;
  const int tid = threadIdx.x;

  if (bid < 384) {
    // ---- pack all 4 weight tensors -> f16 single plane, swizzled layout
    int t = bid * 256 + tid;
    const float* w; u16* dst; int IC, tt;
    if (t < 32768)      { w = wq1; dst = pq1; IC = 256; tt = t; }
    else if (t < 49152) { w = wq2; dst = pq2; IC = 128; tt = t - 32768; }
    else if (t < 81920) { w = wk1; dst = pk1; IC = 256; tt = t - 49152; }
    else                { w = wk2; dst = pk2; IC = 128; tt = t - 81920; }
    const int oc = tt / IC, ic = tt % IC;
    const int ICB = IC >> 5;
    const int ocl = oc & 31, ocq = oc >> 5;
    const int icb = ic >> 5, icl = ic & 31;
    const int swz = ((ocl << 5) | icl) ^ ((ocl & 7) << 3);
    #pragma unroll
    for (int rs = 0; rs < 9; ++rs) {
      float v = w[(oc * IC + ic) * 9 + rs];
      long base = (long)rs * (ICB * 4096) + (long)icb * 4096
                + (long)ocq * 1024 + swz;
      dst[base] = __builtin_bit_cast(u16, (_Float16)v);
    }
  } else if (bid < 511) {
    // ---- zero halos: units of 32 u16. cum: ypad 17472, xpad 21632,
    // t2k 30368, t1q 32448.
    long u = (long)(bid - 384) * 256 + tid;
    if (u >= 32448) return;
    u16* p; int ICB, H, W2;
    if (u < 17472)      { p = ypad; ICB = 8; H = 32; W2 = 514; }
    else if (u < 21632) { u -= 17472; p = xpad; ICB = 8; H = 64; W2 = 66; }
    else if (u < 30368) { u -= 21632; p = t2k; ICB = 4; H = 32; W2 = 514; }
    else                { u -= 30368; p = t1q; ICB = 4; H = 64; W2 = 66; }
    const int H2 = H + 2;
    const long rowsN = (long)2 * ICB * 2 * W2;
    long base;
    if (u < rowsN) {
      int w = (int)(u % W2);
      int t2 = (int)(u / W2);
      int tb = t2 & 1, icb = (t2 >> 1) % ICB, b = (t2 >> 1) / ICB;
      int h = tb ? H2 - 1 : 0;
      base = ((((long)b * H2 + h) * ICB + icb) * W2 + w) * 32;
    } else {
      long v = u - rowsN;
      int side = (int)(v & 1);
      long v2 = v >> 1;
      int h = 1 + (int)(v2 % H);
      int icb = (int)((v2 / H) % ICB);
      int b = (int)(v2 / ((long)H * ICB));
      int w = side ? W2 - 1 : 0;
      base = ((((long)b * H2 + h) * ICB + icb) * W2 + w) * 32;
    }
    us8 zz = {0, 0, 0, 0, 0, 0, 0, 0};
    #pragma unroll
    for (int j = 0; j < 4; ++j)
      *reinterpret_cast<us8*>(&p[base + j * 8]) = zz;
  } else {
    // ---- transpose/cvt: y -> ypad, x -> xpad (f16 padded), z -> zf16
    const int id = bid - 511;
    const float* src; int C, H, W, wt, cb, bh, mode, H2, W2;
    u16* d16;
    if (id < 8192)       { src = y; C = 256; H = 32; W = 512; wt = id & 15;       cb = (id >> 4) & 7; bh = id >> 7; d16 = ypad; mode = 0; H2 = 34; W2 = 514; }
    else if (id < 10240) { int i2 = id - 8192;  src = x; C = 256; H = 64; W = 64; wt = i2 & 1;  cb = (i2 >> 1) & 7; bh = i2 >> 4; d16 = xpad; mode = 0; H2 = 66; W2 = 66; }
    else                 { int i3 = id - 10240; src = z; C = 128; H = 32; W = 512; wt = i3 & 15; cb = (i3 >> 4) & 3; bh = i3 >> 6; d16 = zf16; mode = 1; H2 = 0; W2 = 0; }
    const int b = bh / H, h = bh % H;
    const int w0 = wt * 32;
    const int tx = tid & 31, ty = tid >> 5;
    #pragma unroll
    for (int k2 = 0; k2 < 4; ++k2) {
      int c = cb * 32 + ty + k2 * 8;
      tile[ty + k2 * 8][tx] = src[(((long)b * C + c) * H + h) * W + w0 + tx];
    }
    __syncthreads();
    const int cp = (tid & 15) * 2;
    const int wl = tid >> 4;
    if (mode == 0) {
      const int ICB = C >> 5;
      #pragma unroll
      for (int half = 0; half < 2; ++half) {
        const int wloc = wl + half * 16;
        unsigned int lo = (unsigned int)__builtin_bit_cast(u16, (_Float16)tile[cp][wloc]);
        unsigned int hi = (unsigned int)__builtin_bit_cast(u16, (_Float16)tile[cp + 1][wloc]);
        long idx = ((((long)b * H2 + h + 1) * ICB + cb) * W2 + (w0 + wloc + 1)) * 32 + cp;
        *reinterpret_cast<unsigned int*>(&d16[idx]) = lo | (hi << 16);
      }
    } else {
      #pragma unroll
      for (int half = 0; half < 2; ++half) {
        const int wloc = wl + half * 16;
        unsigned int lo = (unsigned int)__builtin_bit_cast(u16, (_Float16)tile[cp][wloc]);
        unsigned int hi = (unsigned int)__builtin_bit_cast(u16, (_Float16)tile[cp + 1][wloc]);
        long idx = (((long)b * 32 + h) * 512 + (w0 + wloc)) * 128 + cb * 32 + cp;
        *reinterpret_cast<unsigned int*>(&d16[idx]) = lo | (hi << 16);
      }
    }
  }
}

// ---- merged conv (k wids [0,1024) + q wids [1024,1280)).
// Block: 32 oc (ocq) x 2 rows x 64 px; wave = 1 row x 32 px x 32 oc.
// XCD swizzle: wid = (bid%8)*160 + bid/8 (bijective, 1280 % 8 == 0).
// OF16=1: f16 padded out [B][IH+2][4][IW+2][32] + relu.
// OF16=0: f16 flat out [B][IH][IW][128].
template<int ICB, int OF16>
__global__ __launch_bounds__(256, 4) void conv_k(
    const u16* __restrict__ inK, const u16* __restrict__ wpkK,
    const float* __restrict__ biasK, u16* __restrict__ outK,
    const u16* __restrict__ inQ, const u16* __restrict__ wpkQ,
    const float* __restrict__ biasQ, u16* __restrict__ outQ)
{
  __shared__ __align__(16) u16 smem[9216];   // 18432 B: 9 rs x 1024 (32oc x 32ic)

  const int tid = threadIdx.x;
  const int lane = tid & 63, wv = tid >> 6;
  const int lm = lane & 15, lq = lane >> 4;
  // XCD-aware bijective swizzle: blocks sharing input land on one XCD's L2.
  const int bid = blockIdx.x;
  const int wid = (bid & 7) * 160 + (bid >> 3);

  const u16* in; const u16* wpk; const float* bias; u16* outp;
  int IH, IW, w0, hb, b, ocq;
  constexpr int PXS = 64, RPB = 2;
  if (wid < 1024) {
    in = inK; wpk = wpkK; bias = biasK; outp = outK;
    IH = 32; IW = 512;
    b = wid >> 9; hb = ((wid >> 5) & 15) * 2;
    w0 = ((wid >> 2) & 7) * 64; ocq = wid & 3;
  } else {
    const int qb = wid - 1024;
    in = inQ; wpk = wpkQ; bias = biasQ; outp = outQ;
    IH = 64; IW = 64;
    b = qb >> 7; hb = ((qb >> 2) & 31) * 2;
    w0 = 0; ocq = qb & 3;
  }
  const int H2 = IH + 2, W2 = IW + 2;
  const int rp = wv >> 1;               // wave's row within block (0..1)
  const int pxw = (wv & 1) * 32;        // wave's 32-px group

  // A-frag swizzled offsets (mf=0/1); (16+lm)&7 == lm&7 so mf=1 is +512.
  const int aswz0 = (lm * 32 + lq * 8) ^ ((lm & 7) << 3);
  const int aswz1 = aswz0 + 512;

  f32x4 acc[2][2];   // [mf][f]
  #pragma unroll
  for (int mf = 0; mf < 2; ++mf)
    #pragma unroll
    for (int f = 0; f < 2; ++f) acc[mf][f] = (f32x4)0.f;

  for (int icb = 0; icb < ICB; ++icb) {
    __syncthreads();
    // ---- stage this icb's 9 pre-swizzled 32x32 weight tiles (linear copy)
    #pragma unroll
    for (int c0 = 0; c0 < 5; ++c0) {
      const int c = c0 * 256 + tid;
      if (c < 1152) {
        const int rs2 = c >> 7;
        const int j = (c & 127) * 8;
        *reinterpret_cast<uint4*>(&smem[rs2 * 1024 + j]) =
            *reinterpret_cast<const uint4*>(
                wpk + (long)rs2 * (ICB * 4096) + (long)icb * 4096 + ocq * 1024 + j);
      }
    }
    // ---- per-lane row base pointers (padded rows hb+rp .. hb+rp+2)
    const u16* rb[3];
    #pragma unroll
    for (int r = 0; r < 3; ++r)
      rb[r] = in + ((((long)b * H2 + hb + rp + r) * ICB + icb) * W2 + (w0 + pxw + lm)) * 32
            + lq * 8;
    __syncthreads();

    #pragma unroll
    for (int r = 0; r < 3; ++r)
      #pragma unroll
      for (int s = 0; s < 3; ++s) {
        const int rs = r * 3 + s;
        const f16x8 bb0 = *reinterpret_cast<const f16x8*>(rb[r] + s * 32);
        const f16x8 bb1 = *reinterpret_cast<const f16x8*>(rb[r] + (16 + s) * 32);
        const int tb = rs * 1024;
        const f16x8 a0 = *reinterpret_cast<const f16x8*>(&smem[tb + aswz0]);
        const f16x8 a1 = *reinterpret_cast<const f16x8*>(&smem[tb + aswz1]);
        acc[0][0] = MFMA16F(a0, bb0, acc[0][0]);
        acc[0][1] = MFMA16F(a0, bb1, acc[0][1]);
        acc[1][0] = MFMA16F(a1, bb0, acc[1][0]);
        acc[1][1] = MFMA16F(a1, bb1, acc[1][1]);
      }
  }

  // ---- epilogue: bias (+relu for OF16), swizzled LDS staging, f16 write
  __syncthreads();
  u16* st = smem;   // [RPB][PXS][32] u16 (8 KB)
  #pragma unroll
  for (int mf = 0; mf < 2; ++mf)
    #pragma unroll
    for (int f = 0; f < 2; ++f)
      #pragma unroll
      for (int reg = 0; reg < 4; ++reg) {
        const int ocl = mf * 16 + lq * 4 + reg;
        const int px = pxw + f * 16 + lm;
        float v = acc[mf][f][reg] + bias[ocq * 32 + ocl];
        if (OF16) v = fmaxf(v, 0.f);
        st[(rp * PXS + px) * 32 + (ocl ^ ((px & 3) << 3))] =
            __builtin_bit_cast(u16, (_Float16)v);
      }
  __syncthreads();
  const int tot = RPB * PXS * 4;   // us8 chunks
  for (int i = tid; i < tot; i += 256) {
    const int o8 = i & 3, pxr = i >> 2;
    const int px = pxr % PXS, row = pxr / PXS;
    us8 val = *reinterpret_cast<const us8*>(
        &st[(row * PXS + px) * 32 + ((o8 * 8) ^ ((px & 3) << 3))]);
    u16* dst;
    if (OF16)
      dst = outp + ((((long)b * H2 + hb + row + 1) * 4 + ocq) * W2 + (w0 + px + 1)) * 32
          + o8 * 8;
    else
      dst = outp + (((long)b * IH + hb + row) * IW + w0 + px) * 128 + ocq * 32 + o8 * 8;
    *reinterpret_cast<us8*>(dst) = val;
  }
}

// ---- attention: one block per (b, n). 128 threads. All operands f16.
__global__ __launch_bounds__(128) void attn_k(
    const u16* __restrict__ qf, const u16* __restrict__ kf,
    const u16* __restrict__ zf, const int* __restrict__ u,
    float* __restrict__ out)
{
  constexpr float SCALE = 0.08838834764831845f;  // 128^-0.5
  const int n = blockIdx.x, b = blockIdx.y;
  const int t = threadIdx.x;

  __shared__ float qs[128];
  __shared__ float logit[32];
  __shared__ float el[32];

  int widx = u[b * 4096 + n];
  widx = widx < 0 ? 0 : (widx > 511 ? 511 : widx);

  qs[t] = (float)__builtin_bit_cast(_Float16, qf[((long)b * 4096 + n) * 128 + t]);
  __syncthreads();

  const int h = t >> 2, quad = t & 3;
  const u16* kcol = kf + (((long)b * 32 + h) * 512 + widx) * 128 + quad * 32;
  float p = 0.f;
  #pragma unroll
  for (int j = 0; j < 32; j += 8) {
    f16x8 kv = *reinterpret_cast<const f16x8*>(kcol + j);
    #pragma unroll
    for (int jj = 0; jj < 8; ++jj)
      p = fmaf(qs[quad * 32 + j + jj], (float)kv[jj], p);
  }
  p += __shfl_xor(p, 1);
  p += __shfl_xor(p, 2);
  if (quad == 0) logit[h] = p * SCALE;
  __syncthreads();

  float m = -3.4e38f;
  #pragma unroll
  for (int h2 = 0; h2 < 32; ++h2) m = fmaxf(m, logit[h2]);
  if (t < 32) el[t] = __expf(logit[t] - m);
  __syncthreads();
  float den = 0.f;
  #pragma unroll
  for (int h2 = 0; h2 < 32; ++h2) den += el[h2];

  const u16* zcol = zf + ((long)b * 32 * 512) * 128 + (long)widx * 128 + t;
  float o0 = 0.f, o1 = 0.f, o2 = 0.f, o3 = 0.f;
  #pragma unroll
  for (int h2 = 0; h2 < 32; h2 += 4) {
    o0 = fmaf(el[h2 + 0], (float)__builtin_bit_cast(_Float16, zcol[(long)(h2 + 0) * 512 * 128]), o0);
    o1 = fmaf(el[h2 + 1], (float)__builtin_bit_cast(_Float16, zcol[(long)(h2 + 1) * 512 * 128]), o1);
    o2 = fmaf(el[h2 + 2], (float)__builtin_bit_cast(_Float16, zcol[(long)(h2 + 2) * 512 * 128]), o2);
    o3 = fmaf(el[h2 + 3], (float)__builtin_bit_cast(_Float16, zcol[(long)(h2 + 3) * 512 * 128]), o3);
  }
  out[((long)b * 4096 + n) * 128 + t] = ((o0 + o1) + (o2 + o3)) / den;
}

extern "C" void kernel_launch(void* const* d_in, const int* in_sizes, int n_in,
                              void* d_out, int out_size, void* d_ws, size_t ws_size,
                              hipStream_t stream) {
  const float* x   = (const float*)d_in[0];
  const float* y   = (const float*)d_in[1];
  const float* z   = (const float*)d_in[2];
  const int*   u   = (const int*)  d_in[3];
  const float* wq1 = (const float*)d_in[4];
  const float* bq1 = (const float*)d_in[5];
  const float* wq2 = (const float*)d_in[6];
  const float* bq2 = (const float*)d_in[7];
  const float* wk1 = (const float*)d_in[8];
  const float* bk1 = (const float*)d_in[9];
  const float* wk2 = (const float*)d_in[10];
  const float* bk2 = (const float*)d_in[11];
  float* out = (float*)d_out;
  u16* wsu = (u16*)d_ws;

  // ---- arena (u16 offsets); total 54.2 MB
  u16* ypad  = wsu + 0;           //  8,947,712  [2][34][8][514][32] f16
  u16* xpad  = wsu + 8947712;     //  2,230,272  [2][66][8][66][32]  f16
  u16* t2k   = wsu + 11177984;    //  4,473,856  [2][34][4][514][32] f16
  u16* t1q   = wsu + 15651840;    //  1,115,136  [2][66][4][66][32]  f16
  u16* zf16  = wsu + 16766976;    //  4,194,304  [2][32][512][128]   f16
  u16* k_f16 = wsu + 20961280;    //  4,194,304  [2][32][512][128]   f16
  u16* q_f16 = wsu + 25155584;    //  1,048,576  [2,4096,128]        f16
  u16* wpk_q1 = wsu + 26204160;   //    294,912  (pre-swizzled)
  u16* wpk_q2 = wsu + 26499072;   //    147,456
  u16* wpk_k1 = wsu + 26646528;   //    294,912
  u16* wpk_k2 = wsu + 26941440;   //    147,456  -> end 27,088,896 u16

  prep_k<<<dim3(14847), 256, 0, stream>>>(x, y, z, wq1, wq2, wk1, wk2,
                                          wpk_q1, wpk_q2, wpk_k1, wpk_k2,
                                          ypad, xpad, t2k, t1q, zf16);
  conv_k<8, 1><<<dim3(1280), 256, 0, stream>>>(
      ypad, wpk_k1, bk1, t2k, xpad, wpk_q1, bq1, t1q);
  conv_k<4, 0><<<dim3(1280), 256, 0, stream>>>(
      t2k, wpk_k2, bk2, k_f16, t1q, wpk_q2, bq2, q_f16);
  attn_k<<<dim3(4096, 2), 128, 0, stream>>>(q_f16, k_f16, zf16, u, out);
}

// Round 13
// 94.493 us; speedup vs baseline: 1.5923x; 1.2485x over previous
//
#include <hip/hip_runtime.h>

// ---------------------------------------------------------------------------
// x [2,256,64,64]  y [2,256,32,512]  z [2,128,32,512]  u [2,64,64] int
// wq1/wk1 [128,256,3,3]  wq2/wk2 [128,128,3,3]  biases [128]   out [2,4096,128]
//
// Single-plane f16 MFMA convs, fp32 accumulation. Activations halo-padded
// [B][H+2][IC/32][W+2][32] f16 (zero halos -> no bounds checks).
// Conv: wave = 1 row x 32 px x 64 oc (8 MFMA per 2 B-loads + 4 ds_reads —
// 2x FLOP per L1 byte vs 32-oc waves); block = 4 waves = 2 rows x 64 px x
// 64 oc; grid 640, XCD-swizzled (80-wid contiguous slice/XCD, ~3.2 MB L2-fit).
// Weights LDS-staged pre-swizzled (36.9 KB/block).
// 4 launches: prep, conv1, conv2, attn.
// ---------------------------------------------------------------------------

typedef __attribute__((ext_vector_type(8))) _Float16 f16x8;
typedef __attribute__((ext_vector_type(4))) float f32x4;
typedef __attribute__((ext_vector_type(8))) unsigned short us8;
typedef unsigned short u16;

#define MFMA16F(A, B, C) __builtin_amdgcn_mfma_f32_16x16x32_f16((A), (B), (C), 0, 0, 0)

// Weight layout (pre-swizzled, single plane): flat(rs,icb,ocq,j) =
//   rs*(ICB*4096) + icb*4096 + ocq*1024 + j,
// j = ((ocl*32 + ic) ^ ((ocl&7)<<3)), ocl in [0,32), ic in [0,32). (bijective)
// Activation layout: FL(b,hp,icb,wp,c) = (((b*H2+hp)*ICB+icb)*W2+wp)*32 + c.

// ---- merged prep: pack weights [0,384) + zero halos [384,511) + cvt [511,14847)
__global__ __launch_bounds__(256) void prep_k(
    const float* __restrict__ x, const float* __restrict__ y,
    const float* __restrict__ z,
    const float* __restrict__ wq1, const float* __restrict__ wq2,
    const float* __restrict__ wk1, const float* __restrict__ wk2,
    u16* __restrict__ pq1, u16* __restrict__ pq2,
    u16* __restrict__ pk1, u16* __restrict__ pk2,
    u16* __restrict__ ypad, u16* __restrict__ xpad,
    u16* __restrict__ t2k, u16* __restrict__ t1q,
    u16* __restrict__ zf16)
{
  __shared__ float tile[32][33];
  const int bid = blockIdx.x;
  const int tid = threadIdx.x;

  if (bid < 384) {
    // ---- pack all 4 weight tensors -> f16 single plane, swizzled layout
    int t = bid * 256 + tid;
    const float* w; u16* dst; int IC, tt;
    if (t < 32768)      { w = wq1; dst = pq1; IC = 256; tt = t; }
    else if (t < 49152) { w = wq2; dst = pq2; IC = 128; tt = t - 32768; }
    else if (t < 81920) { w = wk1; dst = pk1; IC = 256; tt = t - 49152; }
    else                { w = wk2; dst = pk2; IC = 128; tt = t - 81920; }
    const int oc = tt / IC, ic = tt % IC;
    const int ICB = IC >> 5;
    const int ocl = oc & 31, ocq = oc >> 5;
    const int icb = ic >> 5, icl = ic & 31;
    const int swz = ((ocl << 5) | icl) ^ ((ocl & 7) << 3);
    #pragma unroll
    for (int rs = 0; rs < 9; ++rs) {
      float v = w[(oc * IC + ic) * 9 + rs];
      long base = (long)rs * (ICB * 4096) + (long)icb * 4096
                + (long)ocq * 1024 + swz;
      dst[base] = __builtin_bit_cast(u16, (_Float16)v);
    }
  } else if (bid < 511) {
    // ---- zero halos: units of 32 u16. cum: ypad 17472, xpad 21632,
    // t2k 30368, t1q 32448.
    long u = (long)(bid - 384) * 256 + tid;
    if (u >= 32448) return;
    u16* p; int ICB, H, W2;
    if (u < 17472)      { p = ypad; ICB = 8; H = 32; W2 = 514; }
    else if (u < 21632) { u -= 17472; p = xpad; ICB = 8; H = 64; W2 = 66; }
    else if (u < 30368) { u -= 21632; p = t2k; ICB = 4; H = 32; W2 = 514; }
    else                { u -= 30368; p = t1q; ICB = 4; H = 64; W2 = 66; }
    const int H2 = H + 2;
    const long rowsN = (long)2 * ICB * 2 * W2;
    long base;
    if (u < rowsN) {
      int w = (int)(u % W2);
      int t2 = (int)(u / W2);
      int tb = t2 & 1, icb = (t2 >> 1) % ICB, b = (t2 >> 1) / ICB;
      int h = tb ? H2 - 1 : 0;
      base = ((((long)b * H2 + h) * ICB + icb) * W2 + w) * 32;
    } else {
      long v = u - rowsN;
      int side = (int)(v & 1);
      long v2 = v >> 1;
      int h = 1 + (int)(v2 % H);
      int icb = (int)((v2 / H) % ICB);
      int b = (int)(v2 / ((long)H * ICB));
      int w = side ? W2 - 1 : 0;
      base = ((((long)b * H2 + h) * ICB + icb) * W2 + w) * 32;
    }
    us8 zz = {0, 0, 0, 0, 0, 0, 0, 0};
    #pragma unroll
    for (int j = 0; j < 4; ++j)
      *reinterpret_cast<us8*>(&p[base + j * 8]) = zz;
  } else {
    // ---- transpose/cvt: y -> ypad, x -> xpad (f16 padded), z -> zf16
    const int id = bid - 511;
    const float* src; int C, H, W, wt, cb, bh, mode, H2, W2;
    u16* d16;
    if (id < 8192)       { src = y; C = 256; H = 32; W = 512; wt = id & 15;       cb = (id >> 4) & 7; bh = id >> 7; d16 = ypad; mode = 0; H2 = 34; W2 = 514; }
    else if (id < 10240) { int i2 = id - 8192;  src = x; C = 256; H = 64; W = 64; wt = i2 & 1;  cb = (i2 >> 1) & 7; bh = i2 >> 4; d16 = xpad; mode = 0; H2 = 66; W2 = 66; }
    else                 { int i3 = id - 10240; src = z; C = 128; H = 32; W = 512; wt = i3 & 15; cb = (i3 >> 4) & 3; bh = i3 >> 6; d16 = zf16; mode = 1; H2 = 0; W2 = 0; }
    const int b = bh / H, h = bh % H;
    const int w0 = wt * 32;
    const int tx = tid & 31, ty = tid >> 5;
    #pragma unroll
    for (int k2 = 0; k2 < 4; ++k2) {
      int c = cb * 32 + ty + k2 * 8;
      tile[ty + k2 * 8][tx] = src[(((long)b * C + c) * H + h) * W + w0 + tx];
    }
    __syncthreads();
    const int cp = (tid & 15) * 2;
    const int wl = tid >> 4;
    if (mode == 0) {
      const int ICB = C >> 5;
      #pragma unroll
      for (int half = 0; half < 2; ++half) {
        const int wloc = wl + half * 16;
        unsigned int lo = (unsigned int)__builtin_bit_cast(u16, (_Float16)tile[cp][wloc]);
        unsigned int hi = (unsigned int)__builtin_bit_cast(u16, (_Float16)tile[cp + 1][wloc]);
        long idx = ((((long)b * H2 + h + 1) * ICB + cb) * W2 + (w0 + wloc + 1)) * 32 + cp;
        *reinterpret_cast<unsigned int*>(&d16[idx]) = lo | (hi << 16);
      }
    } else {
      #pragma unroll
      for (int half = 0; half < 2; ++half) {
        const int wloc = wl + half * 16;
        unsigned int lo = (unsigned int)__builtin_bit_cast(u16, (_Float16)tile[cp][wloc]);
        unsigned int hi = (unsigned int)__builtin_bit_cast(u16, (_Float16)tile[cp + 1][wloc]);
        long idx = (((long)b * 32 + h) * 512 + (w0 + wloc)) * 128 + cb * 32 + cp;
        *reinterpret_cast<unsigned int*>(&d16[idx]) = lo | (hi << 16);
      }
    }
  }
}

// ---- merged conv (k wids [0,512) + q wids [512,640)).
// Block: 64 oc (ocsel) x 2 rows x 64 px; wave = 1 row x 32 px x 64 oc.
// XCD swizzle: wid = (bid%8)*80 + bid/8 (bijective, 640 % 8 == 0).
// OF16=1: f16 padded out [B][IH+2][4][IW+2][32] + relu.
// OF16=0: f16 flat out [B][IH][IW][128].
template<int ICB, int OF16>
__global__ __launch_bounds__(256, 3) void conv_k(
    const u16* __restrict__ inK, const u16* __restrict__ wpkK,
    const float* __restrict__ biasK, u16* __restrict__ outK,
    const u16* __restrict__ inQ, const u16* __restrict__ wpkQ,
    const float* __restrict__ biasQ, u16* __restrict__ outQ)
{
  __shared__ __align__(16) u16 smem[18432];   // 36864 B: 9 rs x 2 tiles x 1024

  const int tid = threadIdx.x;
  const int lane = tid & 63, wv = tid >> 6;
  const int lm = lane & 15, lq = lane >> 4;
  const int bid = blockIdx.x;
  const int wid = (bid & 7) * 80 + (bid >> 3);

  const u16* in; const u16* wpk; const float* bias; u16* outp;
  int IH, IW, w0, hb, b, ocsel;
  if (wid < 512) {
    in = inK; wpk = wpkK; bias = biasK; outp = outK;
    IH = 32; IW = 512;
    b = wid >> 8; hb = ((wid >> 4) & 15) * 2;
    w0 = ((wid >> 1) & 7) * 64; ocsel = wid & 1;
  } else {
    const int qb = wid - 512;
    in = inQ; wpk = wpkQ; bias = biasQ; outp = outQ;
    IH = 64; IW = 64;
    b = qb >> 6; hb = ((qb >> 1) & 31) * 2;
    w0 = 0; ocsel = qb & 1;
  }
  const int H2 = IH + 2, W2 = IW + 2;
  const int rp = wv >> 1;               // wave's row within block (0..1)
  const int pxw = (wv & 1) * 32;        // wave's 32-px group

  // A-frag swizzled base; mf=1 at +512 ((16+lm)&7 == lm&7), tile 1 at +1024.
  const int aswz0 = (lm * 32 + lq * 8) ^ ((lm & 7) << 3);

  f32x4 acc[4][2];   // [mf][f]
  #pragma unroll
  for (int mf = 0; mf < 4; ++mf)
    #pragma unroll
    for (int f = 0; f < 2; ++f) acc[mf][f] = (f32x4)0.f;

  for (int icb = 0; icb < ICB; ++icb) {
    __syncthreads();
    // ---- stage this icb's 9 rs x 2 ocq-tiles (pre-swizzled, linear copy)
    #pragma unroll
    for (int c0 = 0; c0 < 9; ++c0) {
      const int c = c0 * 256 + tid;        // 2304 uint4 chunks exactly
      const int t16 = c >> 7;              // rs*2 + tile
      const int j = (c & 127) * 8;
      const int rs2 = t16 >> 1, tt = t16 & 1;
      *reinterpret_cast<uint4*>(&smem[rs2 * 2048 + tt * 1024 + j]) =
          *reinterpret_cast<const uint4*>(
              wpk + (long)rs2 * (ICB * 4096) + (long)icb * 4096
                  + (ocsel * 2 + tt) * 1024 + j);
    }
    // ---- per-lane row base pointers (padded rows hb+rp .. hb+rp+2)
    const u16* rb[3];
    #pragma unroll
    for (int r = 0; r < 3; ++r)
      rb[r] = in + ((((long)b * H2 + hb + rp + r) * ICB + icb) * W2 + (w0 + pxw + lm)) * 32
            + lq * 8;
    __syncthreads();

    #pragma unroll
    for (int r = 0; r < 3; ++r)
      #pragma unroll
      for (int s = 0; s < 3; ++s) {
        const int rs = r * 3 + s;
        const f16x8 bb0 = *reinterpret_cast<const f16x8*>(rb[r] + s * 32);
        const f16x8 bb1 = *reinterpret_cast<const f16x8*>(rb[r] + (16 + s) * 32);
        const int base = rs * 2048 + aswz0;
        const f16x8 a0 = *reinterpret_cast<const f16x8*>(&smem[base]);
        const f16x8 a1 = *reinterpret_cast<const f16x8*>(&smem[base + 512]);
        const f16x8 a2 = *reinterpret_cast<const f16x8*>(&smem[base + 1024]);
        const f16x8 a3 = *reinterpret_cast<const f16x8*>(&smem[base + 1536]);
        acc[0][0] = MFMA16F(a0, bb0, acc[0][0]);
        acc[0][1] = MFMA16F(a0, bb1, acc[0][1]);
        acc[1][0] = MFMA16F(a1, bb0, acc[1][0]);
        acc[1][1] = MFMA16F(a1, bb1, acc[1][1]);
        acc[2][0] = MFMA16F(a2, bb0, acc[2][0]);
        acc[2][1] = MFMA16F(a2, bb1, acc[2][1]);
        acc[3][0] = MFMA16F(a3, bb0, acc[3][0]);
        acc[3][1] = MFMA16F(a3, bb1, acc[3][1]);
      }
  }

  // ---- epilogue: bias (+relu for OF16), LDS staging [2][64][72] (16B-align,
  // ~2-way banks), f16 write
  __syncthreads();
  u16* st = smem;
  #pragma unroll
  for (int mf = 0; mf < 4; ++mf)
    #pragma unroll
    for (int f = 0; f < 2; ++f)
      #pragma unroll
      for (int reg = 0; reg < 4; ++reg) {
        const int ocl = mf * 16 + lq * 4 + reg;    // 0..63
        const int px = pxw + f * 16 + lm;
        float v = acc[mf][f][reg] + bias[ocsel * 64 + ocl];
        if (OF16) v = fmaxf(v, 0.f);
        st[(rp * 64 + px) * 72 + ocl] = __builtin_bit_cast(u16, (_Float16)v);
      }
  __syncthreads();
  for (int i = tid; i < 1024; i += 256) {   // 2 rows x 64 px x 8 us8-chunks
    const int o8 = i & 7;
    const int px = (i >> 3) & 63;
    const int row = i >> 9;
    us8 val = *reinterpret_cast<const us8*>(&st[(row * 64 + px) * 72 + o8 * 8]);
    u16* dst;
    if (OF16)
      dst = outp + ((((long)b * H2 + hb + row + 1) * 4 + ocsel * 2 + (o8 >> 2)) * W2
                    + (w0 + px + 1)) * 32 + (o8 & 3) * 8;
    else
      dst = outp + (((long)b * IH + hb + row) * IW + w0 + px) * 128
          + ocsel * 64 + o8 * 8;
    *reinterpret_cast<us8*>(dst) = val;
  }
}

// ---- attention: one block per (b, n). 128 threads. All operands f16.
__global__ __launch_bounds__(128) void attn_k(
    const u16* __restrict__ qf, const u16* __restrict__ kf,
    const u16* __restrict__ zf, const int* __restrict__ u,
    float* __restrict__ out)
{
  constexpr float SCALE = 0.08838834764831845f;  // 128^-0.5
  const int n = blockIdx.x, b = blockIdx.y;
  const int t = threadIdx.x;

  __shared__ float qs[128];
  __shared__ float logit[32];
  __shared__ float el[32];

  int widx = u[b * 4096 + n];
  widx = widx < 0 ? 0 : (widx > 511 ? 511 : widx);

  qs[t] = (float)__builtin_bit_cast(_Float16, qf[((long)b * 4096 + n) * 128 + t]);
  __syncthreads();

  const int h = t >> 2, quad = t & 3;
  const u16* kcol = kf + (((long)b * 32 + h) * 512 + widx) * 128 + quad * 32;
  float p = 0.f;
  #pragma unroll
  for (int j = 0; j < 32; j += 8) {
    f16x8 kv = *reinterpret_cast<const f16x8*>(kcol + j);
    #pragma unroll
    for (int jj = 0; jj < 8; ++jj)
      p = fmaf(qs[quad * 32 + j + jj], (float)kv[jj], p);
  }
  p += __shfl_xor(p, 1);
  p += __shfl_xor(p, 2);
  if (quad == 0) logit[h] = p * SCALE;
  __syncthreads();

  float m = -3.4e38f;
  #pragma unroll
  for (int h2 = 0; h2 < 32; ++h2) m = fmaxf(m, logit[h2]);
  if (t < 32) el[t] = __expf(logit[t] - m);
  __syncthreads();
  float den = 0.f;
  #pragma unroll
  for (int h2 = 0; h2 < 32; ++h2) den += el[h2];

  const u16* zcol = zf + ((long)b * 32 * 512) * 128 + (long)widx * 128 + t;
  float o0 = 0.f, o1 = 0.f, o2 = 0.f, o3 = 0.f;
  #pragma unroll
  for (int h2 = 0; h2 < 32; h2 += 4) {
    o0 = fmaf(el[h2 + 0], (float)__builtin_bit_cast(_Float16, zcol[(long)(h2 + 0) * 512 * 128]), o0);
    o1 = fmaf(el[h2 + 1], (float)__builtin_bit_cast(_Float16, zcol[(long)(h2 + 1) * 512 * 128]), o1);
    o2 = fmaf(el[h2 + 2], (float)__builtin_bit_cast(_Float16, zcol[(long)(h2 + 2) * 512 * 128]), o2);
    o3 = fmaf(el[h2 + 3], (float)__builtin_bit_cast(_Float16, zcol[(long)(h2 + 3) * 512 * 128]), o3);
  }
  out[((long)b * 4096 + n) * 128 + t] = ((o0 + o1) + (o2 + o3)) / den;
}

extern "C" void kernel_launch(void* const* d_in, const int* in_sizes, int n_in,
                              void* d_out, int out_size, void* d_ws, size_t ws_size,
                              hipStream_t stream) {
  const float* x   = (const float*)d_in[0];
  const float* y   = (const float*)d_in[1];
  const float* z   = (const float*)d_in[2];
  const int*   u   = (const int*)  d_in[3];
  const float* wq1 = (const float*)d_in[4];
  const float* bq1 = (const float*)d_in[5];
  const float* wq2 = (const float*)d_in[6];
  const float* bq2 = (const float*)d_in[7];
  const float* wk1 = (const float*)d_in[8];
  const float* bk1 = (const float*)d_in[9];
  const float* wk2 = (const float*)d_in[10];
  const float* bk2 = (const float*)d_in[11];
  float* out = (float*)d_out;
  u16* wsu = (u16*)d_ws;

  // ---- arena (u16 offsets); total 54.2 MB
  u16* ypad  = wsu + 0;           //  8,947,712  [2][34][8][514][32] f16
  u16* xpad  = wsu + 8947712;     //  2,230,272  [2][66][8][66][32]  f16
  u16* t2k   = wsu + 11177984;    //  4,473,856  [2][34][4][514][32] f16
  u16* t1q   = wsu + 15651840;    //  1,115,136  [2][66][4][66][32]  f16
  u16* zf16  = wsu + 16766976;    //  4,194,304  [2][32][512][128]   f16
  u16* k_f16 = wsu + 20961280;    //  4,194,304  [2][32][512][128]   f16
  u16* q_f16 = wsu + 25155584;    //  1,048,576  [2,4096,128]        f16
  u16* wpk_q1 = wsu + 26204160;   //    294,912  (pre-swizzled)
  u16* wpk_q2 = wsu + 26499072;   //    147,456
  u16* wpk_k1 = wsu + 26646528;   //    294,912
  u16* wpk_k2 = wsu + 26941440;   //    147,456  -> end 27,088,896 u16

  prep_k<<<dim3(14847), 256, 0, stream>>>(x, y, z, wq1, wq2, wk1, wk2,
                                          wpk_q1, wpk_q2, wpk_k1, wpk_k2,
                                          ypad, xpad, t2k, t1q, zf16);
  conv_k<8, 1><<<dim3(640), 256, 0, stream>>>(
      ypad, wpk_k1, bk1, t2k, xpad, wpk_q1, bq1, t1q);
  conv_k<4, 0><<<dim3(640), 256, 0, stream>>>(
      t2k, wpk_k2, bk2, k_f16, t1q, wpk_q2, bq2, q_f16);
  attn_k<<<dim3(4096, 2), 128, 0, stream>>>(q_f16, k_f16, zf16, u, out);
}